// Round 8
// baseline (306.101 us; speedup 1.0000x reference)
//
#include <hip/hip_runtime.h>
#include <hip/hip_bf16.h>
#include <stdint.h>

// h [8, 2048, 128] fp32 -> adj = softmax(cos_sim / T) [8, 2048, 2048] fp32
#define NB 8
#define NN 2048
#define ND 128

typedef __attribute__((ext_vector_type(8))) short short8;   // 8 bf16 (MFMA A/B frag)
typedef __attribute__((ext_vector_type(4))) float f32x4;    // MFMA C/D frag

__device__ __forceinline__ uint32_t pack_bf16(float a, float b) {
    unsigned short ua = __builtin_bit_cast(unsigned short, __float2bfloat16(a));
    unsigned short ub = __builtin_bit_cast(unsigned short, __float2bfloat16(b));
    return (uint32_t)ua | ((uint32_t)ub << 16);
}
__device__ __forceinline__ float unpk_lo(uint32_t p) { return __builtin_bit_cast(float, p << 16); }
__device__ __forceinline__ float unpk_hi(uint32_t p) { return __builtin_bit_cast(float, p & 0xffff0000u); }

// Kernel 1: fp32 row-normalize -> bf16 hn in workspace.
__global__ __launch_bounds__(256) void adjnorm_kernel(const float* __restrict__ h,
                                                      unsigned short* __restrict__ hn) {
    const int row  = blockIdx.x * 4 + (threadIdx.x >> 6);
    const int lane = threadIdx.x & 63;
    const float2 v = reinterpret_cast<const float2*>(h + (size_t)row * ND)[lane];
    float ss = v.x * v.x + v.y * v.y;
    #pragma unroll
    for (int m = 32; m >= 1; m >>= 1) ss += __shfl_xor(ss, m);
    const float nrm = fmaxf(sqrtf(ss), 1e-8f);
    const float inv = 1.0f / nrm;
    reinterpret_cast<uint32_t*>(hn + (size_t)row * ND)[lane] = pack_bf16(v.x * inv, v.y * inv);
}

// ---------------- ABLATION PROBES (outputs overwritten by final adjmain) ----------------

// Probe: pure linear float4 write of the full output buffer -> write-path ceiling.
__global__ __launch_bounds__(256) void probe_store_lin(float* __restrict__ out) {
    const size_t i = (size_t)blockIdx.x * 256 + threadIdx.x;     // float4 index
    const float v = (float)threadIdx.x * 1e-6f;
    const float4 val = make_float4(v, v + 1.f, v + 2.f, v + 3.f);
    float4* o = reinterpret_cast<float4*>(out);
    #pragma unroll
    for (int k = 0; k < 16; ++k)
        o[i + (size_t)k * 524288] = val;    // each k-step: grid writes a contiguous 8 MB span
}

// Probe: round-4 epilogue addressing, same bytes -> store-pattern penalty vs linear.
__global__ __launch_bounds__(512) void probe_store_rd4(float* __restrict__ out) {
    const int b       = blockIdx.y;
    const int rowBase = blockIdx.x * 16;
    const int lane = threadIdx.x & 63;
    const int w    = threadIdx.x >> 6;
    const int l15  = lane & 15;
    const int g    = lane >> 4;
    const float v = (float)threadIdx.x * 1e-6f;
    float* orow = out + ((size_t)b * NN + rowBase + g * 4) * NN + w * 256 + l15;
    #pragma unroll
    for (int t = 0; t < 16; ++t) {
        const int co = t * 16;
        orow[(size_t)0 * NN + co] = v;
        orow[(size_t)1 * NN + co] = v + 1.f;
        orow[(size_t)2 * NN + co] = v + 2.f;
        orow[(size_t)3 * NN + co] = v + 3.f;
    }
}

// Probe: round-4 load+MFMA phase only (no exp/pack/reduce/store). asm keep-alives
// prevent DCE (rule #17). No memory side effects by design.
__global__ __launch_bounds__(512) void probe_gemm(const unsigned short* __restrict__ hn) {
    const int b       = blockIdx.y;
    const int rowBase = blockIdx.x * 16;
    const int lane = threadIdx.x & 63;
    const int w    = threadIdx.x >> 6;
    const int l15  = lane & 15;
    const int g    = lane >> 4;
    const unsigned short* Hb = hn + (size_t)b * NN * ND;

    short8 afrag[4];
    {
        const unsigned short* ap = Hb + (size_t)(rowBase + l15) * ND + g * 8;
        #pragma unroll
        for (int c = 0; c < 4; ++c)
            afrag[c] = *reinterpret_cast<const short8*>(ap + c * 32);
    }
    const unsigned short* colPtr = Hb + (size_t)(w * 256 + l15) * ND + g * 8;
    short8 bA[4], bB[4];

#define LOADB(dst, T) do {                                                      \
        const unsigned short* _bp = colPtr + (size_t)(T) * 16 * ND;             \
        dst[0] = *reinterpret_cast<const short8*>(_bp);                         \
        dst[1] = *reinterpret_cast<const short8*>(_bp + 32);                    \
        dst[2] = *reinterpret_cast<const short8*>(_bp + 64);                    \
        dst[3] = *reinterpret_cast<const short8*>(_bp + 96);                    \
    } while (0)
#define MFMA4(BUF) do {                                                         \
        f32x4 acc = {0.f, 0.f, 0.f, 0.f};                                       \
        acc = __builtin_amdgcn_mfma_f32_16x16x32_bf16(afrag[0], BUF[0], acc, 0, 0, 0); \
        acc = __builtin_amdgcn_mfma_f32_16x16x32_bf16(afrag[1], BUF[1], acc, 0, 0, 0); \
        acc = __builtin_amdgcn_mfma_f32_16x16x32_bf16(afrag[2], BUF[2], acc, 0, 0, 0); \
        acc = __builtin_amdgcn_mfma_f32_16x16x32_bf16(afrag[3], BUF[3], acc, 0, 0, 0); \
        asm volatile("" :: "v"(acc[0]), "v"(acc[1]), "v"(acc[2]), "v"(acc[3])); \
    } while (0)

    LOADB(bA, 0);
    #pragma unroll
    for (int tt = 0; tt < 8; ++tt) {
        LOADB(bB, 2 * tt + 1);
        MFMA4(bA);
        if (tt < 7) LOADB(bA, 2 * tt + 2);
        MFMA4(bB);
    }
#undef LOADB
#undef MFMA4
}

// ---------------- Final real kernel: round-4 structure verbatim (best known, 84 us) ----------------
__global__ __launch_bounds__(512) void adjmain_kernel(const unsigned short* __restrict__ hn,
                                                      const float* __restrict__ tptr,
                                                      float* __restrict__ out) {
    const int b       = blockIdx.y;
    const int rowBase = blockIdx.x * 16;
    const int lane = threadIdx.x & 63;
    const int w    = threadIdx.x >> 6;
    const int l15  = lane & 15;
    const int g    = lane >> 4;

    const float invt = 1.0f / tptr[0];
    const unsigned short* Hb = hn + (size_t)b * NN * ND;

    short8 afrag[4];
    {
        const unsigned short* ap = Hb + (size_t)(rowBase + l15) * ND + g * 8;
        #pragma unroll
        for (int c = 0; c < 4; ++c)
            afrag[c] = *reinterpret_cast<const short8*>(ap + c * 32);
    }

    const unsigned short* colPtr = Hb + (size_t)(w * 256 + l15) * ND + g * 8;

    float rs[4] = {0.f, 0.f, 0.f, 0.f};
    uint32_t pp[16][2];
    short8 bA[4], bB[4];

#define LOADB(dst, T) do {                                                      \
        const unsigned short* _bp = colPtr + (size_t)(T) * 16 * ND;             \
        dst[0] = *reinterpret_cast<const short8*>(_bp);                         \
        dst[1] = *reinterpret_cast<const short8*>(_bp + 32);                    \
        dst[2] = *reinterpret_cast<const short8*>(_bp + 64);                    \
        dst[3] = *reinterpret_cast<const short8*>(_bp + 96);                    \
    } while (0)
#define COMPUTE(T, BUF) do {                                                    \
        f32x4 acc = {0.f, 0.f, 0.f, 0.f};                                       \
        acc = __builtin_amdgcn_mfma_f32_16x16x32_bf16(afrag[0], BUF[0], acc, 0, 0, 0); \
        acc = __builtin_amdgcn_mfma_f32_16x16x32_bf16(afrag[1], BUF[1], acc, 0, 0, 0); \
        acc = __builtin_amdgcn_mfma_f32_16x16x32_bf16(afrag[2], BUF[2], acc, 0, 0, 0); \
        acc = __builtin_amdgcn_mfma_f32_16x16x32_bf16(afrag[3], BUF[3], acc, 0, 0, 0); \
        const float p0 = __expf((acc[0] - 1.0f) * invt);                        \
        const float p1 = __expf((acc[1] - 1.0f) * invt);                        \
        const float p2 = __expf((acc[2] - 1.0f) * invt);                        \
        const float p3 = __expf((acc[3] - 1.0f) * invt);                        \
        rs[0] += p0; rs[1] += p1; rs[2] += p2; rs[3] += p3;                     \
        pp[T][0] = pack_bf16(p0, p1);                                           \
        pp[T][1] = pack_bf16(p2, p3);                                           \
    } while (0)

    LOADB(bA, 0);
    #pragma unroll
    for (int tt = 0; tt < 8; ++tt) {
        LOADB(bB, 2 * tt + 1);
        COMPUTE(2 * tt, bA);
        if (tt < 7) LOADB(bA, 2 * tt + 2);
        COMPUTE(2 * tt + 1, bB);
    }
#undef LOADB
#undef COMPUTE

    #pragma unroll
    for (int r = 0; r < 4; ++r) {
        #pragma unroll
        for (int m = 1; m < 16; m <<= 1) rs[r] += __shfl_xor(rs[r], m);
    }

    __shared__ float rsum_lds[8][16];
    if (l15 == 0) {
        #pragma unroll
        for (int r = 0; r < 4; ++r) rsum_lds[w][g * 4 + r] = rs[r];
    }
    __syncthreads();
    float invs[4];
    #pragma unroll
    for (int r = 0; r < 4; ++r) {
        const int rr = g * 4 + r;
        float s = 0.f;
        #pragma unroll
        for (int ww = 0; ww < 8; ++ww) s += rsum_lds[ww][rr];
        invs[r] = 1.0f / s;
    }

    float* orow = out + ((size_t)b * NN + rowBase + g * 4) * NN + w * 256 + l15;
    #pragma unroll
    for (int t = 0; t < 16; ++t) {
        const int co = t * 16;
        orow[(size_t)0 * NN + co] = unpk_lo(pp[t][0]) * invs[0];
        orow[(size_t)1 * NN + co] = unpk_hi(pp[t][0]) * invs[1];
        orow[(size_t)2 * NN + co] = unpk_lo(pp[t][1]) * invs[2];
        orow[(size_t)3 * NN + co] = unpk_hi(pp[t][1]) * invs[3];
    }
}

extern "C" void kernel_launch(void* const* d_in, const int* in_sizes, int n_in,
                              void* d_out, int out_size, void* d_ws, size_t ws_size,
                              hipStream_t stream) {
    const float* h  = (const float*)d_in[0];
    const float* tp = (const float*)d_in[1];
    unsigned short* hn = (unsigned short*)d_ws;     // 4 MB of ws
    float* out = (float*)d_out;

    hipLaunchKernelGGL(adjnorm_kernel, dim3(NB * NN / 4), dim3(256), 0, stream, h, hn);
    // --- ablation probes (results overwritten by final kernel) ---
    hipLaunchKernelGGL(probe_store_lin, dim3(2048), dim3(256), 0, stream, out);
    hipLaunchKernelGGL(probe_store_rd4, dim3(NN / 16, NB), dim3(512), 0, stream, out);
    hipLaunchKernelGGL(probe_gemm,      dim3(NN / 16, NB), dim3(512), 0, stream, hn);
    // --- real kernel (correct output) ---
    hipLaunchKernelGGL(adjmain_kernel,  dim3(NN / 16, NB), dim3(512), 0, stream, hn, tp, out);
}

// Round 9
// 244.702 us; speedup vs baseline: 1.2509x; 1.2509x over previous
//
#include <hip/hip_runtime.h>
#include <hip/hip_bf16.h>
#include <stdint.h>

// h [8, 2048, 128] fp32 -> adj = softmax(cos_sim / T) [8, 2048, 2048] fp32
// Two-pass streaming: pass 1 = row sums of exp((sim-1)/T); pass 2 = recompute
// sim tile-by-tile, scale by precomputed 1/rowsum, store immediately (float4).
// Both passes run the SAME MFMA sequence -> bitwise-identical sim values.
#define NB 8
#define NN 2048
#define ND 128

typedef __attribute__((ext_vector_type(8))) short short8;   // 8 bf16 (MFMA A/B frag)
typedef __attribute__((ext_vector_type(4))) float f32x4;    // MFMA C/D frag

__device__ __forceinline__ uint32_t pack_bf16(float a, float b) {
    unsigned short ua = __builtin_bit_cast(unsigned short, __float2bfloat16(a));
    unsigned short ub = __builtin_bit_cast(unsigned short, __float2bfloat16(b));
    return (uint32_t)ua | ((uint32_t)ub << 16);
}

// Kernel 1: fp32 row-normalize -> bf16 hn in workspace.
__global__ __launch_bounds__(256) void adjnorm_kernel(const float* __restrict__ h,
                                                      unsigned short* __restrict__ hn) {
    const int row  = blockIdx.x * 4 + (threadIdx.x >> 6);
    const int lane = threadIdx.x & 63;
    const float2 v = reinterpret_cast<const float2*>(h + (size_t)row * ND)[lane];
    float ss = v.x * v.x + v.y * v.y;
    #pragma unroll
    for (int m = 32; m >= 1; m >>= 1) ss += __shfl_xor(ss, m);
    const float nrm = fmaxf(sqrtf(ss), 1e-8f);   // torch cosine_similarity eps
    const float inv = 1.0f / nrm;
    reinterpret_cast<uint32_t*>(hn + (size_t)row * ND)[lane] = pack_bf16(v.x * inv, v.y * inv);
}

// Shared geometry for passes 2/3: block = 16 rows x 2048 cols, 4 waves;
// wave w covers cols [w*512, +512) as 32 tiles of 16. Swapped MFMA operands
// (validated round 6: D col = lane&15 = output ROW, D row = g*4+reg = tile col)
// -> each thread owns row (rowBase+l15), 4 consecutive cols -> float4 stores,
// and its 4 acc elements all belong to ONE row -> scalar row-sum.
// Softmax max is the constant 1/T (cos-sim <= 1, diagonal == 1).

// Kernel 2: row sums -> invsum[b][row] = 1 / sum_j exp((s-1)/T).
__global__ __launch_bounds__(256, 4) void rowsum_kernel(const unsigned short* __restrict__ hn,
                                                        const float* __restrict__ tptr,
                                                        float* __restrict__ invsum) {
    const int b       = blockIdx.y;
    const int rowBase = blockIdx.x * 16;
    const int lane = threadIdx.x & 63;
    const int w    = threadIdx.x >> 6;
    const int l15  = lane & 15;
    const int g    = lane >> 4;

    const float invt = 1.0f / tptr[0];
    const unsigned short* Hb = hn + (size_t)b * NN * ND;

    short8 afrag[4];
    {
        const unsigned short* ap = Hb + (size_t)(rowBase + l15) * ND + g * 8;
        #pragma unroll
        for (int c = 0; c < 4; ++c)
            afrag[c] = *reinterpret_cast<const short8*>(ap + c * 32);
    }
    const unsigned short* colPtr = Hb + (size_t)(w * 512 + l15) * ND + g * 8;

    float rsum = 0.f;
    #pragma unroll 8
    for (int t = 0; t < 32; ++t) {
        const unsigned short* bp = colPtr + (size_t)t * 16 * ND;
        short8 bf0 = *reinterpret_cast<const short8*>(bp);
        short8 bf1 = *reinterpret_cast<const short8*>(bp + 32);
        short8 bf2 = *reinterpret_cast<const short8*>(bp + 64);
        short8 bf3 = *reinterpret_cast<const short8*>(bp + 96);
        f32x4 acc = {0.f, 0.f, 0.f, 0.f};
        acc = __builtin_amdgcn_mfma_f32_16x16x32_bf16(bf0, afrag[0], acc, 0, 0, 0);
        acc = __builtin_amdgcn_mfma_f32_16x16x32_bf16(bf1, afrag[1], acc, 0, 0, 0);
        acc = __builtin_amdgcn_mfma_f32_16x16x32_bf16(bf2, afrag[2], acc, 0, 0, 0);
        acc = __builtin_amdgcn_mfma_f32_16x16x32_bf16(bf3, afrag[3], acc, 0, 0, 0);
        rsum += __expf((acc[0] - 1.0f) * invt) + __expf((acc[1] - 1.0f) * invt)
              + __expf((acc[2] - 1.0f) * invt) + __expf((acc[3] - 1.0f) * invt);
    }
    // all 4 acc elems are row l15 -> reduce over the 4 g-groups (col chunks)
    rsum += __shfl_xor(rsum, 16);
    rsum += __shfl_xor(rsum, 32);

    __shared__ float sm[4][16];
    if (lane < 16) sm[w][l15] = rsum;
    __syncthreads();
    if (threadIdx.x < 16) {
        const float s = sm[0][threadIdx.x] + sm[1][threadIdx.x] +
                        sm[2][threadIdx.x] + sm[3][threadIdx.x];
        invsum[(size_t)b * NN + rowBase + threadIdx.x] = 1.0f / s;
    }
}

// Kernel 3: streaming main pass — recompute sim, scale, store per tile.
// No persistent P state -> low VGPR, stores spread across the whole kernel.
__global__ __launch_bounds__(256, 4) void adjmain_kernel(const unsigned short* __restrict__ hn,
                                                         const float* __restrict__ tptr,
                                                         const float* __restrict__ invsum,
                                                         float* __restrict__ out) {
    const int b       = blockIdx.y;
    const int rowBase = blockIdx.x * 16;
    const int lane = threadIdx.x & 63;
    const int w    = threadIdx.x >> 6;
    const int l15  = lane & 15;
    const int g    = lane >> 4;

    const float invt = 1.0f / tptr[0];
    const unsigned short* Hb = hn + (size_t)b * NN * ND;
    const float invs = invsum[(size_t)b * NN + rowBase + l15];   // this thread's row

    short8 afrag[4];
    {
        const unsigned short* ap = Hb + (size_t)(rowBase + l15) * ND + g * 8;
        #pragma unroll
        for (int c = 0; c < 4; ++c)
            afrag[c] = *reinterpret_cast<const short8*>(ap + c * 32);
    }
    const unsigned short* colPtr = Hb + (size_t)(w * 512 + l15) * ND + g * 8;
    float* orow = out + ((size_t)b * NN + rowBase + l15) * NN + w * 512 + g * 4;

    #pragma unroll 8
    for (int t = 0; t < 32; ++t) {
        const unsigned short* bp = colPtr + (size_t)t * 16 * ND;
        short8 bf0 = *reinterpret_cast<const short8*>(bp);
        short8 bf1 = *reinterpret_cast<const short8*>(bp + 32);
        short8 bf2 = *reinterpret_cast<const short8*>(bp + 64);
        short8 bf3 = *reinterpret_cast<const short8*>(bp + 96);
        f32x4 acc = {0.f, 0.f, 0.f, 0.f};
        acc = __builtin_amdgcn_mfma_f32_16x16x32_bf16(bf0, afrag[0], acc, 0, 0, 0);
        acc = __builtin_amdgcn_mfma_f32_16x16x32_bf16(bf1, afrag[1], acc, 0, 0, 0);
        acc = __builtin_amdgcn_mfma_f32_16x16x32_bf16(bf2, afrag[2], acc, 0, 0, 0);
        acc = __builtin_amdgcn_mfma_f32_16x16x32_bf16(bf3, afrag[3], acc, 0, 0, 0);
        const float4 v = make_float4(__expf((acc[0] - 1.0f) * invt) * invs,
                                     __expf((acc[1] - 1.0f) * invt) * invs,
                                     __expf((acc[2] - 1.0f) * invt) * invs,
                                     __expf((acc[3] - 1.0f) * invt) * invs);
        *reinterpret_cast<float4*>(orow + t * 16) = v;    // dwordx4, streams out
    }
}

extern "C" void kernel_launch(void* const* d_in, const int* in_sizes, int n_in,
                              void* d_out, int out_size, void* d_ws, size_t ws_size,
                              hipStream_t stream) {
    const float* h  = (const float*)d_in[0];
    const float* tp = (const float*)d_in[1];
    unsigned short* hn = (unsigned short*)d_ws;                        // 4 MB
    float* invsum = (float*)((char*)d_ws + (size_t)NB * NN * ND * 2);  // 64 KB @ +4 MB
    float* out = (float*)d_out;

    hipLaunchKernelGGL(adjnorm_kernel, dim3(NB * NN / 4), dim3(256), 0, stream, h, hn);
    hipLaunchKernelGGL(rowsum_kernel,  dim3(NN / 16, NB), dim3(256), 0, stream, hn, tp, invsum);
    hipLaunchKernelGGL(adjmain_kernel, dim3(NN / 16, NB), dim3(256), 0, stream, hn, tp, invsum, out);
}